// Round 1
// 1824.867 us; speedup vs baseline: 1.3116x; 1.3116x over previous
//
#include <hip/hip_runtime.h>
#include <hip/hip_bf16.h>
#include <math.h>
#include <stdint.h>

typedef __bf16 bf16_t;
typedef __bf16 bf16x8 __attribute__((ext_vector_type(8)));
typedef __bf16 bf16x4v __attribute__((ext_vector_type(4)));
typedef float f32x4 __attribute__((ext_vector_type(4)));

#define BB 4
#define SS 2048
#define DD 1024
#define HH 16
#define SCALE 0.125f   // 1/sqrt(64)
static constexpr size_t NE = (size_t)BB * SS * DD;   // 8388608
static constexpr size_t WN = (size_t)DD * DD;        // 1048576

// ---------------- helpers ----------------
__device__ inline f32x4 load4f(const bf16_t* p) {
    bf16x4v v = *(const bf16x4v*)p;
    return (f32x4){(float)v[0], (float)v[1], (float)v[2], (float)v[3]};
}
__device__ inline f32x4 load4f(const float* p) { return *(const f32x4*)p; }
__device__ inline void store4(bf16_t* p, f32x4 v) {
    bf16x4v o;
    for (int j = 0; j < 4; ++j) o[j] = (bf16_t)v[j];
    *(bf16x4v*)p = o;
}
__device__ inline void store4(float* p, f32x4 v) { *(f32x4*)p = v; }
__device__ inline void store16(bf16_t* p, const bf16_t* s) {
    *(bf16x8*)p       = *(const bf16x8*)s;
    *(bf16x8*)(p + 8) = *(const bf16x8*)(s + 8);
}
__device__ inline void store16(float* p, const bf16_t* s) {
    for (int j = 0; j < 16; j += 4) {
        f32x4 v = {(float)s[j], (float)s[j + 1], (float)s[j + 2], (float)s[j + 3]};
        *(f32x4*)(p + j) = v;
    }
}
__device__ inline void cvt8(const float* s, bf16_t* d) {
    f32x4 a = *(const f32x4*)s;
    f32x4 b = *(const f32x4*)(s + 4);
    bf16x8 r;
    for (int j = 0; j < 4; ++j) { r[j] = (bf16_t)a[j]; r[4 + j] = (bf16_t)b[j]; }
    *(bf16x8*)d = r;
}
// async global->LDS, 16B per lane; l must be wave-uniform (HW: base + lane*16)
__device__ __forceinline__ void async16(const bf16_t* g, bf16_t* l) {
    __builtin_amdgcn_global_load_lds(
        (const __attribute__((address_space(1))) void*)g,
        (__attribute__((address_space(3))) void*)l, 16, 0, 0);
}
// 16-lane butterfly reductions via DPP (VALU latency, not LDS latency)
__device__ __forceinline__ float dpp_max16(float x) {
    x = fmaxf(x, __int_as_float(__builtin_amdgcn_update_dpp(0, __float_as_int(x), 0xB1,  0xF, 0xF, true)));
    x = fmaxf(x, __int_as_float(__builtin_amdgcn_update_dpp(0, __float_as_int(x), 0x4E,  0xF, 0xF, true)));
    x = fmaxf(x, __int_as_float(__builtin_amdgcn_update_dpp(0, __float_as_int(x), 0x141, 0xF, 0xF, true)));
    x = fmaxf(x, __int_as_float(__builtin_amdgcn_update_dpp(0, __float_as_int(x), 0x140, 0xF, 0xF, true)));
    return x;
}
__device__ __forceinline__ float dpp_add16(float x) {
    x += __int_as_float(__builtin_amdgcn_update_dpp(0, __float_as_int(x), 0xB1,  0xF, 0xF, true));
    x += __int_as_float(__builtin_amdgcn_update_dpp(0, __float_as_int(x), 0x4E,  0xF, 0xF, true));
    x += __int_as_float(__builtin_amdgcn_update_dpp(0, __float_as_int(x), 0x141, 0xF, 0xF, true));
    x += __int_as_float(__builtin_amdgcn_update_dpp(0, __float_as_int(x), 0x140, 0xF, 0xF, true));
    return x;
}

// ---------------------------------------------------------------------------
// Probe: flags[0] = input float dtype (0=bf16, 1=fp32)
//        flags[1] = mask layout (0=byte, 1=int32, 2=int64)
// ---------------------------------------------------------------------------
__global__ void probe_kernel(const uint16_t* __restrict__ q,
                             const uint8_t* __restrict__ m,
                             int* __restrict__ flags)
{
    __shared__ int s_f32, s_byte, s_i32;
    if (threadIdx.x == 0) { s_f32 = 0; s_byte = 0; s_i32 = 0; }
    __syncthreads();
    {
        unsigned bits = ((unsigned)q[threadIdx.x]) << 16;
        float f = __uint_as_float(bits);
        if (!(fabsf(f) < 1e10f)) atomicOr(&s_f32, 1);
    }
    for (int j = threadIdx.x; j < 4096; j += 256) {
        if (m[j]) {
            if (j & 3) atomicOr(&s_byte, 1);
            else if ((j & 7) == 4) atomicOr(&s_i32, 1);
        }
    }
    __syncthreads();
    if (threadIdx.x == 0) {
        flags[0] = s_f32 ? 1 : 0;
        flags[1] = s_byte ? 0 : (s_i32 ? 1 : 2);
    }
}

// ---------------------------------------------------------------------------
// fp32 -> bf16 conversion (fp32 chain only)
// ---------------------------------------------------------------------------
__global__ __launch_bounds__(256) void cvt_qkv(
    const float* __restrict__ q, const float* __restrict__ k,
    const float* __restrict__ v, bf16_t* __restrict__ dst,
    const int* __restrict__ flags)
{
    if (flags[0] != 1) return;
    size_t i = ((size_t)blockIdx.x * 256 + threadIdx.x) * 8;
    const float* src;
    size_t off;
    if (i < NE)          { src = q; off = i; }
    else if (i < 2 * NE) { src = k; off = i - NE; }
    else                 { src = v; off = i - 2 * NE; }
    cvt8(src + off, dst + i);
}

__global__ __launch_bounds__(256) void cvt_w(
    const float* __restrict__ Wq, const float* __restrict__ Wk,
    const float* __restrict__ Wv, const float* __restrict__ Wo,
    const float* __restrict__ bq, const float* __restrict__ bk,
    const float* __restrict__ bv, const float* __restrict__ bo,
    bf16_t* __restrict__ dst, const int* __restrict__ flags)
{
    if (flags[0] != 1) return;
    size_t i = ((size_t)blockIdx.x * 256 + threadIdx.x) * 8;
    const float* src;
    size_t off;
    const size_t W4 = 4 * WN;
    if (i < W4) {
        int ws = (int)(i >> 20);
        src = ws == 0 ? Wq : ws == 1 ? Wk : ws == 2 ? Wv : Wo;
        off = i & (WN - 1);
    } else {
        size_t j = i - W4;
        int bs = (int)(j >> 10);
        src = bs == 0 ? bq : bs == 1 ? bk : bs == 2 ? bv : bo;
        off = j & 1023;
    }
    cvt8(src + off, dst + i);
}

// ---------------------------------------------------------------------------
// Y[m][n] = A[m,:] . B[n,:] + bias   (all bf16, fp32 accumulate)
// m97 structure: 128x128 tile, BK=64, linear LDS, global_load_lds x16B.
// BIAS_ROW=0: bias[n] (normal X*W^T+b). BIAS_ROW=1: bias[m] (swapped-operand
// call producing a transposed output, used to emit V^T directly).
// ---------------------------------------------------------------------------
template<int BIAS_ROW>
__global__ __launch_bounds__(256) void gemm_bt_bias(
    const bf16_t* __restrict__ A, const bf16_t* __restrict__ B,
    const bf16_t* __restrict__ bias, bf16_t* __restrict__ Y,
    int M, int N, int K, const int* __restrict__ flags, int want)
{
    if (flags[0] != want) return;

    __shared__ __align__(16) bf16_t As[128 * 64];
    __shared__ __align__(16) bf16_t Bs[128 * 64];

    const int tid = threadIdx.x;
    const int wave = tid >> 6;
    const int lane = tid & 63;
    const int quad = lane >> 4;
    const int l15  = lane & 15;
    const int wm = wave >> 1, wn = wave & 1;

    const int m0 = blockIdx.y * 128;
    const int n0 = blockIdx.x * 128;

    f32x4 acc[4][4];
    #pragma unroll
    for (int i = 0; i < 4; ++i)
        #pragma unroll
        for (int j = 0; j < 4; ++j)
            acc[i][j] = (f32x4){0.f, 0.f, 0.f, 0.f};

    for (int k0 = 0; k0 < K; k0 += 64) {
        __syncthreads();
        #pragma unroll
        for (int s = 0; s < 4; ++s) {
            int c = s * 256 + wave * 64 + lane;          // 16B chunk index
            int row = c >> 3, col = (c & 7) * 8;
            bf16_t* la = &As[(size_t)(s * 256 + wave * 64) * 8];   // wave-uniform
            bf16_t* lb = &Bs[(size_t)(s * 256 + wave * 64) * 8];
            async16(&A[(size_t)(m0 + row) * K + k0 + col], la);
            async16(&B[(size_t)(n0 + row) * K + k0 + col], lb);
        }
        __syncthreads();   // compiler emits vmcnt(0) drain before barrier
        bf16x8 a0[4], a1[4], b0[4], b1[4];
        #pragma unroll
        for (int mt = 0; mt < 4; ++mt) {
            const bf16_t* p = &As[(size_t)(wm * 64 + mt * 16 + l15) * 64 + quad * 8];
            a0[mt] = *(const bf16x8*)p;
            a1[mt] = *(const bf16x8*)(p + 32);
        }
        #pragma unroll
        for (int nt = 0; nt < 4; ++nt) {
            const bf16_t* p = &Bs[(size_t)(wn * 64 + nt * 16 + l15) * 64 + quad * 8];
            b0[nt] = *(const bf16x8*)p;
            b1[nt] = *(const bf16x8*)(p + 32);
        }
        #pragma unroll
        for (int mt = 0; mt < 4; ++mt)
            #pragma unroll
            for (int nt = 0; nt < 4; ++nt) {
                acc[mt][nt] = __builtin_amdgcn_mfma_f32_16x16x32_bf16(a0[mt], b0[nt], acc[mt][nt], 0, 0, 0);
                acc[mt][nt] = __builtin_amdgcn_mfma_f32_16x16x32_bf16(a1[mt], b1[nt], acc[mt][nt], 0, 0, 0);
            }
    }

    float brow[4][4];
    if (BIAS_ROW) {
        #pragma unroll
        for (int mt = 0; mt < 4; ++mt)
            #pragma unroll
            for (int r = 0; r < 4; ++r)
                brow[mt][r] = (float)bias[m0 + wm * 64 + mt * 16 + quad * 4 + r];
    }
    #pragma unroll
    for (int nt = 0; nt < 4; ++nt) {
        int n = n0 + wn * 64 + nt * 16 + l15;
        float bn = BIAS_ROW ? 0.f : (float)bias[n];
        #pragma unroll
        for (int mt = 0; mt < 4; ++mt) {
            int mbase = m0 + wm * 64 + mt * 16 + quad * 4;
            #pragma unroll
            for (int r = 0; r < 4; ++r) {
                float bv = BIAS_ROW ? brow[mt][r] : bn;
                Y[(size_t)(mbase + r) * N + n] = (bf16_t)(acc[mt][nt][r] + bv);
            }
        }
    }
}

// ---------------------------------------------------------------------------
// Fused attention: per (b,h,64-row q-tile). Two-pass softmax.
// Vt is V^T, layout [(d_full)*BB + b][s]  (emitted by the swapped V-GEMM).
// Mask staged per-tile as 64 x uint64 row-bitmasks (coalesced uint4 loads).
// Softmax reductions via DPP butterflies (no ds_bpermute chains).
// ---------------------------------------------------------------------------
template<typename T>
__global__ __launch_bounds__(256, 4) void attn_fused(
    const bf16_t* Qp, const bf16_t* __restrict__ Kp, const bf16_t* __restrict__ Vt,
    const void* maskp, const int* __restrict__ flags, int want,
    T* __restrict__ attn_out, bf16_t* ctx_out)
{
    if (flags[0] != want) return;

    __shared__ __align__(16) bf16_t Ks[64][72];
    __shared__ __align__(16) bf16_t Ps[64][72];
    __shared__ __align__(16) bf16_t QV[64][72];   // Q staging, then V^T tile
    __shared__ uint64_t Msk[64];

    const int tid  = threadIdx.x;
    const int wave = tid >> 6;
    const int lane = tid & 63;
    const int quad = lane >> 4;
    const int l15  = lane & 15;
    const int qt = blockIdx.x;
    const int bh = blockIdx.y;
    const int b  = bh / HH;
    const int h  = bh % HH;
    const int q0 = qt * 64;

    const int mmode = flags[1];
    const uint8_t*  m8  = (const uint8_t*)maskp;
    const uint32_t* m32 = (const uint32_t*)maskp;
    const size_t mbase = (size_t)b * SS * SS;
    const int rowl_base = wave * 16 + quad * 4;   // block-local q-row of acc r=0
    const int qrow_base = q0 + rowl_base;

    // stage K tile + mask tile (as row bitmasks) for k-tile kt
    auto stage_k_mask = [&](int kt) {
        #pragma unroll
        for (int j = 0; j < 2; ++j) {
            int c = tid * 2 + j;
            int row = c >> 3, cc = (c & 7) * 8;
            *(bf16x8*)&Ks[row][cc] =
                *(const bf16x8*)&Kp[(size_t)(b * SS + kt * 64 + row) * DD + h * 64 + cc];
        }
        int row = tid >> 2, ch = tid & 3;          // 4 threads/row, 16 cols each
        size_t e = mbase + (size_t)(q0 + row) * SS + kt * 64 + ch * 16;
        uint32_t bits = 0;
        if (mmode == 0) {
            uint4 v = *(const uint4*)(m8 + e);
            uint32_t w0 = v.x, w1 = v.y, w2 = v.z, w3 = v.w;
            bits |= ((w0 & 0x000000ffu) ? 1u : 0u) << 0;
            bits |= ((w0 & 0x0000ff00u) ? 1u : 0u) << 1;
            bits |= ((w0 & 0x00ff0000u) ? 1u : 0u) << 2;
            bits |= ((w0 & 0xff000000u) ? 1u : 0u) << 3;
            bits |= ((w1 & 0x000000ffu) ? 1u : 0u) << 4;
            bits |= ((w1 & 0x0000ff00u) ? 1u : 0u) << 5;
            bits |= ((w1 & 0x00ff0000u) ? 1u : 0u) << 6;
            bits |= ((w1 & 0xff000000u) ? 1u : 0u) << 7;
            bits |= ((w2 & 0x000000ffu) ? 1u : 0u) << 8;
            bits |= ((w2 & 0x0000ff00u) ? 1u : 0u) << 9;
            bits |= ((w2 & 0x00ff0000u) ? 1u : 0u) << 10;
            bits |= ((w2 & 0xff000000u) ? 1u : 0u) << 11;
            bits |= ((w3 & 0x000000ffu) ? 1u : 0u) << 12;
            bits |= ((w3 & 0x0000ff00u) ? 1u : 0u) << 13;
            bits |= ((w3 & 0x00ff0000u) ? 1u : 0u) << 14;
            bits |= ((w3 & 0xff000000u) ? 1u : 0u) << 15;
        } else if (mmode == 1) {
            const uint32_t* p = m32 + e;
            #pragma unroll
            for (int w = 0; w < 16; w += 4) {
                uint4 v = *(const uint4*)(p + w);
                bits |= (v.x ? 1u : 0u) << (w + 0);
                bits |= (v.y ? 1u : 0u) << (w + 1);
                bits |= (v.z ? 1u : 0u) << (w + 2);
                bits |= (v.w ? 1u : 0u) << (w + 3);
            }
        } else {
            const uint32_t* p = m32 + 2 * e;       // int64: test low word
            #pragma unroll
            for (int g = 0; g < 16; g += 2) {
                uint4 v = *(const uint4*)(p + 2 * g);
                bits |= (v.x ? 1u : 0u) << (g + 0);
                bits |= (v.z ? 1u : 0u) << (g + 1);
            }
        }
        ((uint16_t*)Msk)[row * 4 + ch] = (uint16_t)bits;
    };

    // ---- stage Q tile once; hoist A-fragments into registers ----
    #pragma unroll
    for (int j = 0; j < 2; ++j) {
        int c = tid * 2 + j;
        int row = c >> 3, cc = (c & 7) * 8;
        *(bf16x8*)&QV[row][cc] =
            *(const bf16x8*)&Qp[(size_t)(b * SS + q0 + row) * DD + h * 64 + cc];
    }
    __syncthreads();
    const bf16x8 aq0 = *(const bf16x8*)&QV[wave * 16 + l15][quad * 8];
    const bf16x8 aq1 = *(const bf16x8*)&QV[wave * 16 + l15][32 + quad * 8];

    float mrow[4], lrow[4];
    #pragma unroll
    for (int r = 0; r < 4; ++r) { mrow[r] = -INFINITY; lrow[r] = 0.f; }

    // ---------------- PASS 1: row max + denom ----------------
    for (int kt = 0; kt < 32; ++kt) {
        __syncthreads();
        stage_k_mask(kt);
        __syncthreads();
        float sv[4][4];
        #pragma unroll
        for (int nt = 0; nt < 4; ++nt) {
            bf16x8 b0 = *(const bf16x8*)&Ks[nt * 16 + l15][quad * 8];
            bf16x8 b1 = *(const bf16x8*)&Ks[nt * 16 + l15][32 + quad * 8];
            f32x4 s = (f32x4){0.f, 0.f, 0.f, 0.f};
            s = __builtin_amdgcn_mfma_f32_16x16x32_bf16(aq0, b0, s, 0, 0, 0);
            s = __builtin_amdgcn_mfma_f32_16x16x32_bf16(aq1, b1, s, 0, 0, 0);
            #pragma unroll
            for (int r = 0; r < 4; ++r) sv[nt][r] = s[r];
        }
        #pragma unroll
        for (int r = 0; r < 4; ++r) {
            uint64_t mb = Msk[rowl_base + r];
            float x[4]; bool mk[4];
            float mloc = -INFINITY;
            #pragma unroll
            for (int nt = 0; nt < 4; ++nt) {
                mk[nt] = (mb >> (nt * 16 + l15)) & 1ull;
                x[nt] = mk[nt] ? -INFINITY : sv[nt][r] * SCALE;
                mloc = fmaxf(mloc, x[nt]);
            }
            float mnew = fmaxf(mrow[r], dpp_max16(mloc));
            float ps = 0.f;
            #pragma unroll
            for (int nt = 0; nt < 4; ++nt)
                ps += mk[nt] ? 0.f : __expf(x[nt] - mnew);
            ps = dpp_add16(ps);
            float alpha = (mrow[r] == mnew) ? 1.f : __expf(mrow[r] - mnew);
            lrow[r] = lrow[r] * alpha + ps;
            mrow[r] = mnew;
        }
    }

    float rinv[4];
    #pragma unroll
    for (int r = 0; r < 4; ++r) rinv[r] = (lrow[r] > 0.f) ? 1.f / lrow[r] : 0.f;

    f32x4 cacc[4];
    #pragma unroll
    for (int dt = 0; dt < 4; ++dt) cacc[dt] = (f32x4){0.f, 0.f, 0.f, 0.f};

    // ---------------- PASS 2: normalized P, attn store, PV ----------------
    for (int kt = 0; kt < 32; ++kt) {
        __syncthreads();
        stage_k_mask(kt);
        #pragma unroll
        for (int j = 0; j < 2; ++j) {   // stage V^T tile (coalesced copy)
            int c = tid * 2 + j;
            int row = c >> 3, cc = (c & 7) * 8;
            *(bf16x8*)&QV[row][cc] =
                *(const bf16x8*)&Vt[((size_t)(h * 64 + row) * BB + b) * SS + kt * 64 + cc];
        }
        __syncthreads();
        float sv[4][4];
        #pragma unroll
        for (int nt = 0; nt < 4; ++nt) {
            bf16x8 b0 = *(const bf16x8*)&Ks[nt * 16 + l15][quad * 8];
            bf16x8 b1 = *(const bf16x8*)&Ks[nt * 16 + l15][32 + quad * 8];
            f32x4 s = (f32x4){0.f, 0.f, 0.f, 0.f};
            s = __builtin_amdgcn_mfma_f32_16x16x32_bf16(aq0, b0, s, 0, 0, 0);
            s = __builtin_amdgcn_mfma_f32_16x16x32_bf16(aq1, b1, s, 0, 0, 0);
            #pragma unroll
            for (int r = 0; r < 4; ++r) sv[nt][r] = s[r];
        }
        #pragma unroll
        for (int r = 0; r < 4; ++r) {
            uint64_t mb = Msk[rowl_base + r];
            #pragma unroll
            for (int nt = 0; nt < 4; ++nt) {
                bool mk = (mb >> (nt * 16 + l15)) & 1ull;
                float p = mk ? 0.f : __expf(sv[nt][r] * SCALE - mrow[r]) * rinv[r];
                Ps[rowl_base + r][nt * 16 + l15] = (bf16_t)p;
            }
        }
        __syncthreads();
        bf16x8 ap0 = *(const bf16x8*)&Ps[wave * 16 + l15][quad * 8];
        bf16x8 ap1 = *(const bf16x8*)&Ps[wave * 16 + l15][32 + quad * 8];
        #pragma unroll
        for (int dt = 0; dt < 4; ++dt) {
            bf16x8 bv0 = *(const bf16x8*)&QV[dt * 16 + l15][quad * 8];
            bf16x8 bv1 = *(const bf16x8*)&QV[dt * 16 + l15][32 + quad * 8];
            cacc[dt] = __builtin_amdgcn_mfma_f32_16x16x32_bf16(ap0, bv0, cacc[dt], 0, 0, 0);
            cacc[dt] = __builtin_amdgcn_mfma_f32_16x16x32_bf16(ap1, bv1, cacc[dt], 0, 0, 0);
        }
        {   // coalesced attn store, head-major [(h*B+b)][q][k]
            int row = tid >> 2;
            int ch  = (tid & 3) * 16;
            size_t dst = ((size_t)(h * BB + b) * SS + (q0 + row)) * SS + kt * 64 + ch;
            store16(&attn_out[dst], &Ps[row][ch]);
        }
    }

    #pragma unroll
    for (int dt = 0; dt < 4; ++dt)
        #pragma unroll
        for (int r = 0; r < 4; ++r)
            ctx_out[(size_t)(b * SS + qrow_base + r) * DD + h * 64 + dt * 16 + l15] =
                (bf16_t)cacc[dt][r];
}

// ---------------------------------------------------------------------------
// out = LN(proj + query) * gamma + beta   (proj bf16 scratch, already has +bo)
// ---------------------------------------------------------------------------
template<typename T>
__global__ __launch_bounds__(256) void ln_kernel(
    const bf16_t* __restrict__ P, const T* __restrict__ Qr,
    const T* __restrict__ gamma, const T* __restrict__ beta,
    T* __restrict__ out, const int* __restrict__ flags, int want)
{
    if (flags[0] != want) return;
    const int row = blockIdx.x;
    const int tid = threadIdx.x;
    const size_t base = (size_t)row * DD + tid * 4;
    f32x4 pv = load4f(&P[base]);
    f32x4 qv = load4f(&Qr[base]);
    float x[4]; float s = 0.f, s2 = 0.f;
    for (int j = 0; j < 4; ++j) {
        x[j] = pv[j] + qv[j];
        s += x[j]; s2 += x[j] * x[j];
    }
    for (int off = 1; off < 64; off <<= 1) {
        s  += __shfl_xor(s, off);
        s2 += __shfl_xor(s2, off);
    }
    __shared__ float sh[8];
    const int wave = tid >> 6, lane = tid & 63;
    if (lane == 0) { sh[wave] = s; sh[4 + wave] = s2; }
    __syncthreads();
    s  = sh[0] + sh[1] + sh[2] + sh[3];
    s2 = sh[4] + sh[5] + sh[6] + sh[7];
    float mean = s * (1.0f / DD);
    float var  = s2 * (1.0f / DD) - mean * mean;
    float inv  = rsqrtf(var + 1e-5f);
    f32x4 g  = load4f(&gamma[tid * 4]);
    f32x4 bt = load4f(&beta[tid * 4]);
    f32x4 o;
    for (int j = 0; j < 4; ++j)
        o[j] = g[j] * (x[j] - mean) * inv + bt[j];
    store4(&out[base], o);
}

// ---------------------------------------------------------------------------
template<typename T>
static void run_chain(void* const* d_in, void* d_out, bf16_t* Qp, bf16_t* Kp,
                      int* flags, int want, hipStream_t stream)
{
    const T* query = (const T*)d_in[0];
    const void* mask = d_in[3];
    const T* gamma = (const T*)d_in[12];
    const T* beta  = (const T*)d_in[13];

    T* out  = (T*)d_out;
    T* attn = out + NE;
    bf16_t* Vp = (bf16_t*)d_out;        // V^T scratch in the LN-output region
    const int M = BB * SS;

    const bf16_t *qb, *kb, *vb, *Wqb, *Wkb, *Wvb, *Wob, *bqb, *bkb, *bvb, *bob;
    if constexpr (sizeof(T) == 4) {
        // fp32 chain: convert inputs once to bf16 scratch.
        // qkv -> attn region (free until attn_fused writes it, which is after
        // the projection GEMMs consume them). W/b -> out region after Vp
        // (free until LN, which runs after the Wo GEMM consumes them).
        bf16_t* S0 = (bf16_t*)attn;
        bf16_t* WB = Vp + NE;
        cvt_qkv<<<dim3(3 * 4096), 256, 0, stream>>>(
            (const float*)d_in[0], (const float*)d_in[1], (const float*)d_in[2], S0, flags);
        cvt_w<<<dim3(2050), 256, 0, stream>>>(
            (const float*)d_in[4], (const float*)d_in[6], (const float*)d_in[8], (const float*)d_in[10],
            (const float*)d_in[5], (const float*)d_in[7], (const float*)d_in[9], (const float*)d_in[11],
            WB, flags);
        qb = S0; kb = S0 + NE; vb = S0 + 2 * NE;
        Wqb = WB; Wkb = WB + WN; Wvb = WB + 2 * WN; Wob = WB + 3 * WN;
        bqb = WB + 4 * WN; bkb = bqb + 1024; bvb = bqb + 2048; bob = bqb + 3072;
    } else {
        qb  = (const bf16_t*)d_in[0]; kb  = (const bf16_t*)d_in[1]; vb  = (const bf16_t*)d_in[2];
        Wqb = (const bf16_t*)d_in[4]; bqb = (const bf16_t*)d_in[5];
        Wkb = (const bf16_t*)d_in[6]; bkb = (const bf16_t*)d_in[7];
        Wvb = (const bf16_t*)d_in[8]; bvb = (const bf16_t*)d_in[9];
        Wob = (const bf16_t*)d_in[10]; bob = (const bf16_t*)d_in[11];
    }

    dim3 gg(DD / 128, M / 128);
    gemm_bt_bias<0><<<gg, 256, 0, stream>>>(qb, Wqb, bqb, Qp, M, DD, DD, flags, want);
    gemm_bt_bias<0><<<gg, 256, 0, stream>>>(kb, Wkb, bkb, Kp, M, DD, DD, flags, want);
    // swapped operands -> writes V^T (rows=d, cols=b*S+s), bias per row
    gemm_bt_bias<1><<<dim3(M / 128, DD / 128), 256, 0, stream>>>(
        Wvb, vb, bvb, Vp, DD, M, DD, flags, want);

    attn_fused<T><<<dim3(SS / 64, BB * HH), 256, 0, stream>>>(
        Qp, Kp, Vp, mask, flags, want, attn, Qp);

    gemm_bt_bias<0><<<gg, 256, 0, stream>>>(Qp, Wob, bob, Kp, M, DD, DD, flags, want);

    ln_kernel<T><<<M, 256, 0, stream>>>(Kp, query, gamma, beta, out, flags, want);
}

extern "C" void kernel_launch(void* const* d_in, const int* in_sizes, int n_in,
                              void* d_out, int out_size, void* d_ws, size_t ws_size,
                              hipStream_t stream)
{
    int* flags = (int*)d_ws;
    bf16_t* Qp = (bf16_t*)((char*)d_ws + 16);
    bf16_t* Kp = Qp + NE;

    probe_kernel<<<1, 256, 0, stream>>>((const uint16_t*)d_in[0],
                                        (const uint8_t*)d_in[3], flags);

    run_chain<bf16_t>(d_in, d_out, Qp, Kp, flags, 0, stream);
    run_chain<float >(d_in, d_out, Qp, Kp, flags, 1, stream);
}